// Round 6
// baseline (15.606 us; speedup 1.0000x reference)
//
#include <hip/hip_runtime.h>
#include <hip/hip_bf16.h>
#include <stdint.h>

#define NPTS 8192
#define DIM  64
#define NB   4
#define KK   9
#define TQ   64       // queries per tile
#define NT   2        // tiles per block (128 queries/block, 256 blocks)
#define RROWS 224     // rolling rows: m = n0-90+r
#define SD2  72       // stage row stride in bf16 elems (144 B, 16B-aligned)
#define UD2  91       // key stride per query (uints): wofs 0..89 + pad

typedef short bf16x8 __attribute__((ext_vector_type(8)));
typedef float f32x4  __attribute__((ext_vector_type(4)));

// 2-tile pipelined fused KNN (256 blocks x 512 thr, 1 block/CU):
//   stage1 rows 0..159 + psum -> bar1 -> T1 A-frags || rn reduce -> bar2 ->
//   issue T2 row loads (regs) ; T1 MFMA+pack -> bar3 -> T1 select+out ;
//   cvt T2 regs -> sb rows 160..223 + psC -> bar4 -> T2 A-frags || rn2 reduce ->
//   bar5 -> T2 MFMA+pack -> bar6 -> T2 select+out.
// Row r <-> m = n0-90+r. Tile t query q (n = n0+64t+q) = row 64t+q+90;
// window wofs in [0,89] = row 64t+q+1+wofs; rel = r-64t-q-1.
// Garbage rows (clamped addrs) are MFMA-read but never packed (rel>89) or are
// masked in selection (m>=0) - no load masking anywhere.
__global__ __launch_bounds__(512, 2) void knn_fused(const float* __restrict__ x,
                                                    int* __restrict__ out) {
    __shared__ ushort   sb[RROWS * SD2];   // 32256 B staged bf16 rows
    __shared__ uint32_t ud[TQ * UD2];      // 23296 B keys [q][wofs], reused per tile
    __shared__ float    rnArr[RROWS];      // 896 B inverse norms
    __shared__ float2   psA[512];          // 4096 B partials rows 0..127
    __shared__ float2   psB[128];          // 1024 B partials rows 128..159
    __shared__ float2   psC[256];          // 2048 B partials rows 160..223

    const int tid = threadIdx.x;
    // XCD-chunked swizzle: same-XCD blocks take consecutive tiles -> window L2 hits
    const int blk = blockIdx.x;
    const int L   = (blk & 7) * 32 + (blk >> 3);   // bijective on 256 blocks
    const int b   = L >> 6;                        // 64 double-tiles per batch
    const int n0  = (L & 63) << 7;
    const int gbase = n0 - 90;                     // EVEN

    const float* xb = x + (size_t)b * DIM * NPTS;

    const int w = tid >> 6;
    const int l = tid & 63;

    // ---- stage1 region 1: rows 0..127 as 64 lane-pairs; wave w covers d in [8w,8w+7] ----
    {
        const int g2 = l * 2;
        const int gg = gbase + g2;
        const int gs = (gg < 0) ? 0 : gg;
        const float* src = xb + gs;
        float s0 = 0.f, s1 = 0.f;
        uint32_t pkA[4], pkB[4];
#pragma unroll
        for (int e = 0; e < 4; ++e) {
            const int d = 8 * w + 2 * e;
            float2 v = *reinterpret_cast<const float2*>(&src[(size_t)d * NPTS]);
            float2 u = *reinterpret_cast<const float2*>(&src[(size_t)(d + 1) * NPTS]);
            s0 += v.x * v.x + u.x * u.x;
            s1 += v.y * v.y + u.y * u.y;
            __hip_bfloat162 hA = __float22bfloat162_rn(make_float2(v.x, u.x));
            __hip_bfloat162 hB = __float22bfloat162_rn(make_float2(v.y, u.y));
            pkA[e] = *reinterpret_cast<uint32_t*>(&hA);
            pkB[e] = *reinterpret_cast<uint32_t*>(&hB);
        }
        *reinterpret_cast<uint4*>(&sb[(size_t)g2 * SD2 + 8 * w]) =
            make_uint4(pkA[0], pkA[1], pkA[2], pkA[3]);
        *reinterpret_cast<uint4*>(&sb[(size_t)(g2 + 1) * SD2 + 8 * w]) =
            make_uint4(pkB[0], pkB[1], pkB[2], pkB[3]);
        psA[tid] = make_float2(s0, s1);
    }
    // ---- stage1 region 2: rows 128..159 as 16 lane-pairs x 32 d-pairs ----
    {
        const int g2 = 128 + (l & 15) * 2;
        const int c  = (w << 2) | (l >> 4);        // 0..31: d pair (2c, 2c+1)
        const int gg = gbase + g2;
        const int gs = (gg > NPTS - 2) ? (NPTS - 2) : gg;
        const float* src = xb + gs;
        float2 v = *reinterpret_cast<const float2*>(&src[(size_t)(2 * c) * NPTS]);
        float2 u = *reinterpret_cast<const float2*>(&src[(size_t)(2 * c + 1) * NPTS]);
        float s0 = v.x * v.x + u.x * u.x;
        float s1 = v.y * v.y + u.y * u.y;
        __hip_bfloat162 hA = __float22bfloat162_rn(make_float2(v.x, u.x));
        __hip_bfloat162 hB = __float22bfloat162_rn(make_float2(v.y, u.y));
        *reinterpret_cast<uint32_t*>(&sb[(size_t)g2 * SD2 + 2 * c]) =
            *reinterpret_cast<uint32_t*>(&hA);
        *reinterpret_cast<uint32_t*>(&sb[(size_t)(g2 + 1) * SD2 + 2 * c]) =
            *reinterpret_cast<uint32_t*>(&hB);
        s0 += __shfl_xor(s0, 16); s0 += __shfl_xor(s0, 32);
        s1 += __shfl_xor(s1, 16); s1 += __shfl_xor(s1, 32);
        if (l < 16) psB[w * 16 + l] = make_float2(s0, s1);
    }
    __syncthreads();   // bar1: sb rows 0..159 + psA/psB visible

    const int qt = w >> 1;            // query tile 0..3
    const int h  = w & 1;             // row-tile half
    const int lr = l & 15;
    const int lk = l >> 4;
    const int nrt = 4 - h;            // 4 or 3 row tiles
    const int q0 = qt * 16 + lk * 4;

    // ---- T1 A-frag prefetch || rn reduce rows 0..159 ----
    const ushort* ap1 = &sb[(size_t)(90 + qt * 16 + lr) * SD2 + lk * 8];
    bf16x8 a0 = *reinterpret_cast<const bf16x8*>(ap1);
    bf16x8 a1 = *reinterpret_cast<const bf16x8*>(ap1 + 32);

    if (tid < 128) {
        const int gp = tid >> 1, comp = tid & 1;
        float s = 0.f;
#pragma unroll
        for (int k = 0; k < 8; ++k)
            s += reinterpret_cast<const float*>(&psA[k * 64 + gp])[comp];
        rnArr[tid] = 1.0f / fmaxf(sqrtf(s), 1e-12f);
    } else if (tid < 160) {
        const int rr = tid - 128;
        const int gp = rr >> 1, comp = rr & 1;
        float s = 0.f;
#pragma unroll
        for (int k = 0; k < 8; ++k)
            s += reinterpret_cast<const float*>(&psB[k * 16 + gp])[comp];
        rnArr[tid] = 1.0f / fmaxf(sqrtf(s), 1e-12f);
    }
    __syncthreads();   // bar2: rnArr[0..159] visible

    // ---- issue T2 stage loads into registers (rows 160..223, lanes l<32) ----
    float2 t2v[4], t2u[4];
    const bool t2act = (l < 32);
    {
        const int g2 = 160 + 2 * (l & 31);
        int gg = gbase + g2;
        int gs = (gg > NPTS - 2) ? (NPTS - 2) : gg;
        const float* src = xb + gs;
#pragma unroll
        for (int e = 0; e < 4; ++e) {
            const int d = 8 * w + 2 * e;
            if (t2act) {
                t2v[e] = *reinterpret_cast<const float2*>(&src[(size_t)d * NPTS]);
                t2u[e] = *reinterpret_cast<const float2*>(&src[(size_t)(d + 1) * NPTS]);
            }
        }
    }

    // ---- T1 banded MFMA + key pack (bt = 0) ----
    {
        float rq[4];
#pragma unroll
        for (int j = 0; j < 4; ++j) rq[j] = rnArr[90 + q0 + j];
#pragma unroll
        for (int i = 0; i < 4; ++i) {
            if (i < nrt) {
                const int rto = h * 4 + i;
                const int rbase = qt * 16 + rto * 16;
                const ushort* bp = &sb[(size_t)(rbase + lr) * SD2 + lk * 8];
                bf16x8 b0 = *reinterpret_cast<const bf16x8*>(bp);
                bf16x8 b1 = *reinterpret_cast<const bf16x8*>(bp + 32);
                f32x4 acc = {0.f, 0.f, 0.f, 0.f};
                acc = __builtin_amdgcn_mfma_f32_16x16x32_bf16(a0, b0, acc, 0, 0, 0);
                acc = __builtin_amdgcn_mfma_f32_16x16x32_bf16(a1, b1, acc, 0, 0, 0);
                const int r = rbase + lr;
                const float rnr = rnArr[r];
#pragma unroll
                for (int j = 0; j < 4; ++j) {
                    int rel = r - (q0 + j) - 1;
                    if (rel >= 0 && rel <= 89) {
                        float p = acc[j] * rq[j] * rnr;
                        float dist = 2.0f - 2.0f * p;
                        uint32_t uu = __float_as_uint(dist);
                        uu = (uu & 0x80000000u) ? ~uu : (uu | 0x80000000u);
                        ud[(q0 + j) * UD2 + rel] = (uu & 0xFFFFFF80u) | (uint32_t)rel;
                    }
                }
            }
        }
    }
    __syncthreads();   // bar3: T1 keys visible

    // ---- T1 selection + output (n = n0 + q) ----
    {
        const int ql = l >> 3;
        const int s  = l & 7;
        const int q  = (w << 3) | ql;
        const int n  = n0 + q;

        uint32_t key[12];
#pragma unroll
        for (int t = 0; t < 12; ++t) {
            int wofs = s + 8 * t;
            int m = n - 89 + wofs;
            bool ok = (wofs <= 89) && (m >= 0);
            uint32_t raw = ud[q * UD2 + (ok ? wofs : 0)];
            key[t] = ok ? raw : 0xFFFFFFFFu;
        }

        uint32_t prev = 0;
        int omKeep = n;
        int om8 = n;
#pragma unroll
        for (int j = 0; j < KK; ++j) {
            uint32_t mn = 0xFFFFFFFFu;
#pragma unroll
            for (int t = 0; t < 12; ++t) {
                uint32_t cand = (key[t] > prev) ? key[t] : 0xFFFFFFFFu;
                mn = (cand < mn) ? cand : mn;
            }
            uint32_t o;
            o = (uint32_t)__shfl_xor((int)mn, 1); mn = (o < mn) ? o : mn;
            o = (uint32_t)__shfl_xor((int)mn, 2); mn = (o < mn) ? o : mn;
            o = (uint32_t)__shfl_xor((int)mn, 4); mn = (o < mn) ? o : mn;
            int om = (mn == 0xFFFFFFFFu) ? n : (n - 89 + (int)(mn & 127u));
            if (j < 8) {
                if (s == j) omKeep = om;
            } else {
                om8 = om;
            }
            prev = mn;
        }

        const int base0 = (b * NPTS + n) * KK;
        const int base1 = NB * NPTS * KK + base0;
        out[base0 + s] = omKeep;
        out[base1 + s] = n;
        if (s == 0) {
            out[base0 + 8] = om8;
            out[base1 + 8] = n;
        }
    }

    // ---- cvt T2 regs -> sb rows 160..223 + psC (loads drained under T1 work) ----
    if (t2act) {
        const int g2 = 160 + 2 * (l & 31);
        float s0 = 0.f, s1 = 0.f;
        uint32_t pkA[4], pkB[4];
#pragma unroll
        for (int e = 0; e < 4; ++e) {
            float2 v = t2v[e], u = t2u[e];
            s0 += v.x * v.x + u.x * u.x;
            s1 += v.y * v.y + u.y * u.y;
            __hip_bfloat162 hA = __float22bfloat162_rn(make_float2(v.x, u.x));
            __hip_bfloat162 hB = __float22bfloat162_rn(make_float2(v.y, u.y));
            pkA[e] = *reinterpret_cast<uint32_t*>(&hA);
            pkB[e] = *reinterpret_cast<uint32_t*>(&hB);
        }
        *reinterpret_cast<uint4*>(&sb[(size_t)g2 * SD2 + 8 * w]) =
            make_uint4(pkA[0], pkA[1], pkA[2], pkA[3]);
        *reinterpret_cast<uint4*>(&sb[(size_t)(g2 + 1) * SD2 + 8 * w]) =
            make_uint4(pkB[0], pkB[1], pkB[2], pkB[3]);
        psC[w * 32 + (l & 31)] = make_float2(s0, s1);
    }
    __syncthreads();   // bar4: sb rows 160..223 + psC visible

    // ---- T2 A-frag prefetch || rn reduce rows 160..223 ----
    const ushort* ap2 = &sb[(size_t)(154 + qt * 16 + lr) * SD2 + lk * 8];
    bf16x8 c0 = *reinterpret_cast<const bf16x8*>(ap2);
    bf16x8 c1 = *reinterpret_cast<const bf16x8*>(ap2 + 32);

    if (tid < 64) {
        const int gp = tid >> 1, comp = tid & 1;
        float s = 0.f;
#pragma unroll
        for (int k = 0; k < 8; ++k)
            s += reinterpret_cast<const float*>(&psC[k * 32 + gp])[comp];
        rnArr[160 + tid] = 1.0f / fmaxf(sqrtf(s), 1e-12f);
    }
    __syncthreads();   // bar5: rnArr[160..223] visible; ud free for T2

    // ---- T2 banded MFMA + key pack (bt = 64) ----
    {
        float rq[4];
#pragma unroll
        for (int j = 0; j < 4; ++j) rq[j] = rnArr[154 + q0 + j];
#pragma unroll
        for (int i = 0; i < 4; ++i) {
            if (i < nrt) {
                const int rto = h * 4 + i;
                const int rbase = 64 + qt * 16 + rto * 16;
                const ushort* bp = &sb[(size_t)(rbase + lr) * SD2 + lk * 8];
                bf16x8 b0 = *reinterpret_cast<const bf16x8*>(bp);
                bf16x8 b1 = *reinterpret_cast<const bf16x8*>(bp + 32);
                f32x4 acc = {0.f, 0.f, 0.f, 0.f};
                acc = __builtin_amdgcn_mfma_f32_16x16x32_bf16(c0, b0, acc, 0, 0, 0);
                acc = __builtin_amdgcn_mfma_f32_16x16x32_bf16(c1, b1, acc, 0, 0, 0);
                const int r = rbase + lr;
                const float rnr = rnArr[r];
#pragma unroll
                for (int j = 0; j < 4; ++j) {
                    int rel = r - 64 - (q0 + j) - 1;
                    if (rel >= 0 && rel <= 89) {
                        float p = acc[j] * rq[j] * rnr;
                        float dist = 2.0f - 2.0f * p;
                        uint32_t uu = __float_as_uint(dist);
                        uu = (uu & 0x80000000u) ? ~uu : (uu | 0x80000000u);
                        ud[(q0 + j) * UD2 + rel] = (uu & 0xFFFFFF80u) | (uint32_t)rel;
                    }
                }
            }
        }
    }
    __syncthreads();   // bar6: T2 keys visible

    // ---- T2 selection + output (n = n0 + 64 + q) ----
    {
        const int ql = l >> 3;
        const int s  = l & 7;
        const int q  = (w << 3) | ql;
        const int n  = n0 + 64 + q;

        uint32_t key[12];
#pragma unroll
        for (int t = 0; t < 12; ++t) {
            int wofs = s + 8 * t;
            int m = n - 89 + wofs;
            bool ok = (wofs <= 89) && (m >= 0);
            uint32_t raw = ud[q * UD2 + (ok ? wofs : 0)];
            key[t] = ok ? raw : 0xFFFFFFFFu;
        }

        uint32_t prev = 0;
        int omKeep = n;
        int om8 = n;
#pragma unroll
        for (int j = 0; j < KK; ++j) {
            uint32_t mn = 0xFFFFFFFFu;
#pragma unroll
            for (int t = 0; t < 12; ++t) {
                uint32_t cand = (key[t] > prev) ? key[t] : 0xFFFFFFFFu;
                mn = (cand < mn) ? cand : mn;
            }
            uint32_t o;
            o = (uint32_t)__shfl_xor((int)mn, 1); mn = (o < mn) ? o : mn;
            o = (uint32_t)__shfl_xor((int)mn, 2); mn = (o < mn) ? o : mn;
            o = (uint32_t)__shfl_xor((int)mn, 4); mn = (o < mn) ? o : mn;
            int om = (mn == 0xFFFFFFFFu) ? n : (n - 89 + (int)(mn & 127u));
            if (j < 8) {
                if (s == j) omKeep = om;
            } else {
                om8 = om;
            }
            prev = mn;
        }

        const int base0 = (b * NPTS + n) * KK;
        const int base1 = NB * NPTS * KK + base0;
        out[base0 + s] = omKeep;
        out[base1 + s] = n;
        if (s == 0) {
            out[base0 + 8] = om8;
            out[base1 + 8] = n;
        }
    }
}

extern "C" void kernel_launch(void* const* d_in, const int* in_sizes, int n_in,
                              void* d_out, int out_size, void* d_ws, size_t ws_size,
                              hipStream_t stream) {
    const float* x = (const float*)d_in[0];
    int* out = (int*)d_out;
    knn_fused<<<NB * (NPTS / (TQ * NT)), 512, 0, stream>>>(x, out);
}

// Round 7
// 13.925 us; speedup vs baseline: 1.1207x; 1.1207x over previous
//
#include <hip/hip_runtime.h>
#include <hip/hip_bf16.h>
#include <stdint.h>

#define NPTS 8192
#define DIM  64
#define NB   4
#define KK   9
#define BQ   32       // queries per block
#define RROWS 128     // staged rows: m = n0-90+r; rows 122..127 garbage (never packed)
#define SD2  72       // stage row stride in bf16 elems (144 B, 16B-aligned)
#define UD2  91       // key stride per query (uints): wofs 0..89 + pad

typedef short bf16x8 __attribute__((ext_vector_type(8)));
typedef float f32x4  __attribute__((ext_vector_type(4)));

// BQ=32 / 256-thread / 1024-block variant: 4 blocks/CU for phase-bubble TLP.
//   stage bf16 (float2 pair loads, clamped unmasked) + psum -> bar1 ->
//   A-frag prefetch || rn reduce -> bar2 -> banded MFMA + key pack -> bar3 ->
//   8-lane/query top-9 extraction.
// Row r <-> m = n0-90+r. Query q (n = n0+q) = row q+90; candidate wofs in [0,89]
// = row q+1+wofs; rel = r-q-1. Garbage rows (addr-clamped) are never packed
// (rel>89) or masked in selection (m>=0 check) - no load masking anywhere.
__global__ __launch_bounds__(256, 4) void knn_fused(const float* __restrict__ x,
                                                    int* __restrict__ out) {
    __shared__ ushort   sb[RROWS * SD2];   // 18432 B staged bf16 rows
    __shared__ uint32_t ud[BQ * UD2];      // 11648 B keys [q][wofs]
    __shared__ float2   psA[256];          // 2048 B row-pair partials (16 dims each)
    __shared__ float    rnArr[RROWS];      // 512 B inverse norms

    const int tid = threadIdx.x;
    // XCD-chunked swizzle: same-XCD blocks take consecutive tiles -> window L2 hits
    const int blk = blockIdx.x;
    const int L   = (blk & 7) * 128 + (blk >> 3);  // bijective on 1024 blocks
    const int b   = L >> 8;                        // 256 tiles per batch
    const int n0  = (L & 255) << 5;
    const int gbase = n0 - 90;                     // EVEN

    const float* xb = x + (size_t)b * DIM * NPTS;

    const int w = tid >> 6;                        // wave 0..3
    const int l = tid & 63;

    // ---- stage: rows 0..127 as 64 lane-pairs; wave w covers d in [16w,16w+16) ----
    // Each float2 load: 64 lanes x 8 B consecutive n -> 512 B contiguous segment.
    {
        const int g2 = l * 2;                      // row pair (g2, g2+1)
        int gg = gbase + g2;
        int gs = (gg < 0) ? 0 : ((gg > NPTS - 2) ? (NPTS - 2) : gg);
        const float* src = xb + gs;
        float s0 = 0.f, s1 = 0.f;
        uint32_t pkA[8], pkB[8];
#pragma unroll
        for (int e = 0; e < 8; ++e) {
            const int d = 16 * w + 2 * e;
            float2 v = *reinterpret_cast<const float2*>(&src[(size_t)d * NPTS]);
            float2 u = *reinterpret_cast<const float2*>(&src[(size_t)(d + 1) * NPTS]);
            s0 += v.x * v.x + u.x * u.x;
            s1 += v.y * v.y + u.y * u.y;
            __hip_bfloat162 hA = __float22bfloat162_rn(make_float2(v.x, u.x));
            __hip_bfloat162 hB = __float22bfloat162_rn(make_float2(v.y, u.y));
            pkA[e] = *reinterpret_cast<uint32_t*>(&hA);
            pkB[e] = *reinterpret_cast<uint32_t*>(&hB);
        }
        *reinterpret_cast<uint4*>(&sb[(size_t)g2 * SD2 + 16 * w]) =
            make_uint4(pkA[0], pkA[1], pkA[2], pkA[3]);
        *reinterpret_cast<uint4*>(&sb[(size_t)g2 * SD2 + 16 * w + 8]) =
            make_uint4(pkA[4], pkA[5], pkA[6], pkA[7]);
        *reinterpret_cast<uint4*>(&sb[(size_t)(g2 + 1) * SD2 + 16 * w]) =
            make_uint4(pkB[0], pkB[1], pkB[2], pkB[3]);
        *reinterpret_cast<uint4*>(&sb[(size_t)(g2 + 1) * SD2 + 16 * w + 8]) =
            make_uint4(pkB[4], pkB[5], pkB[6], pkB[7]);
        psA[tid] = make_float2(s0, s1);
    }
    __syncthreads();   // bar1: sb + psA visible

    const int qt = w >> 1;            // query tile 0..1
    const int h  = w & 1;             // row-tile half
    const int lr = l & 15;
    const int lk = l >> 4;
    const int nrt = 4 - h;            // 4 or 3 row tiles (band rows 16qt .. 16qt+111)
    const int q0 = qt * 16 + lk * 4;

    // ---- A-frag prefetch (sb valid) overlapped with inverse-norm reduce ----
    const ushort* ap = &sb[(size_t)(90 + qt * 16 + lr) * SD2 + lk * 8];
    bf16x8 a0 = *reinterpret_cast<const bf16x8*>(ap);
    bf16x8 a1 = *reinterpret_cast<const bf16x8*>(ap + 32);

    if (tid < 128) {
        const int gp = tid >> 1, comp = tid & 1;
        float s = 0.f;
#pragma unroll
        for (int k = 0; k < 4; ++k)
            s += reinterpret_cast<const float*>(&psA[k * 64 + gp])[comp];
        rnArr[tid] = 1.0f / fmaxf(sqrtf(s), 1e-12f);
    }
    __syncthreads();   // bar2: rnArr visible

    // ---- banded MFMA (nrt split) + compact key pack (sb/ud disjoint) ----
    {
        float rq[4];
#pragma unroll
        for (int j = 0; j < 4; ++j) rq[j] = rnArr[90 + q0 + j];
#pragma unroll
        for (int i = 0; i < 4; ++i) {
            if (i < nrt) {
                const int rto = h * 4 + i;
                const int rbase = qt * 16 + rto * 16;
                const ushort* bp = &sb[(size_t)(rbase + lr) * SD2 + lk * 8];
                bf16x8 b0 = *reinterpret_cast<const bf16x8*>(bp);
                bf16x8 b1 = *reinterpret_cast<const bf16x8*>(bp + 32);
                f32x4 acc = {0.f, 0.f, 0.f, 0.f};
                acc = __builtin_amdgcn_mfma_f32_16x16x32_bf16(a0, b0, acc, 0, 0, 0);
                acc = __builtin_amdgcn_mfma_f32_16x16x32_bf16(a1, b1, acc, 0, 0, 0);
                const int r = rbase + lr;
                const float rnr = rnArr[r];
#pragma unroll
                for (int j = 0; j < 4; ++j) {
                    int rel = r - (q0 + j) - 1;      // window offset wofs
                    if (rel >= 0 && rel <= 89) {
                        float p = acc[j] * rq[j] * rnr;
                        float dist = 2.0f - 2.0f * p;
                        uint32_t uu = __float_as_uint(dist);
                        uu = (uu & 0x80000000u) ? ~uu : (uu | 0x80000000u);
                        ud[(q0 + j) * UD2 + rel] = (uu & 0xFFFFFF80u) | (uint32_t)rel;
                    }
                }
            }
        }
    }
    __syncthreads();   // bar3: keys visible

    // ---- selection: 8 lanes per query, 9 rounds of masked-min extraction ----
    {
        const int ql = l >> 3;             // 0..7
        const int s  = l & 7;              // 0..7
        const int q  = (w << 3) | ql;      // 0..31
        const int n  = n0 + q;

        uint32_t key[12];
#pragma unroll
        for (int t = 0; t < 12; ++t) {
            int wofs = s + 8 * t;          // window offset 0..95
            int m = n - 89 + wofs;
            bool ok = (wofs <= 89) && (m >= 0);
            uint32_t raw = ud[q * UD2 + (ok ? wofs : 0)];
            key[t] = ok ? raw : 0xFFFFFFFFu;
        }

        uint32_t prev = 0;
        int omKeep = n;
        int om8 = n;
#pragma unroll
        for (int j = 0; j < KK; ++j) {
            uint32_t mn = 0xFFFFFFFFu;
#pragma unroll
            for (int t = 0; t < 12; ++t) {
                uint32_t cand = (key[t] > prev) ? key[t] : 0xFFFFFFFFu;
                mn = (cand < mn) ? cand : mn;
            }
            uint32_t o;
            o = (uint32_t)__shfl_xor((int)mn, 1); mn = (o < mn) ? o : mn;
            o = (uint32_t)__shfl_xor((int)mn, 2); mn = (o < mn) ? o : mn;
            o = (uint32_t)__shfl_xor((int)mn, 4); mn = (o < mn) ? o : mn;
            int om = (mn == 0xFFFFFFFFu) ? n : (n - 89 + (int)(mn & 127u));
            if (j < 8) {
                if (s == j) omKeep = om;
            } else {
                om8 = om;
            }
            prev = mn;
        }

        const int base0 = (b * NPTS + n) * KK;
        const int base1 = NB * NPTS * KK + base0;
        out[base0 + s] = omKeep;           // 8 coalesced lanes per query
        out[base1 + s] = n;
        if (s == 0) {
            out[base0 + 8] = om8;
            out[base1 + 8] = n;
        }
    }
}

extern "C" void kernel_launch(void* const* d_in, const int* in_sizes, int n_in,
                              void* d_out, int out_size, void* d_ws, size_t ws_size,
                              hipStream_t stream) {
    const float* x = (const float*)d_in[0];
    int* out = (int*)d_out;
    knn_fused<<<NB * (NPTS / BQ), 256, 0, stream>>>(x, out);
}

// Round 8
// 12.995 us; speedup vs baseline: 1.2009x; 1.0716x over previous
//
#include <hip/hip_runtime.h>
#include <hip/hip_bf16.h>
#include <stdint.h>

#define NPTS 8192
#define DIM  64
#define NB   4
#define KK   9
#define BQ   64       // queries per block
#define RROWS 160     // staged rows: m = n0-90+r (row 0 = pad so gbase is EVEN)
#define SD2  72       // stage row stride in bf16 elems (144 B, 16B-aligned)
#define UD2  91       // key stride per query (uints): wofs 0..89 + pad

typedef short bf16x8 __attribute__((ext_vector_type(8)));
typedef float f32x4  __attribute__((ext_vector_type(4)));

static __device__ __forceinline__ uint32_t umin32(uint32_t a, uint32_t b) {
    return a < b ? a : b;
}

// 3-barrier fused KNN (R5 structure = best measured 13.31us), plus:
//  - tree-min (depth 4, v_min3-friendly) candidate reduction in selection
//  - s_setprio(1) around the MFMA+pack cluster (2 blocks/CU drift phases)
//   stage bf16 (float2 pair loads, clamped unmasked) + psum -> bar1 ->
//   A-frag prefetch || psum reduce -> bar2 ->
//   banded MFMA (nrt split) + key pack -> bar3 -> 8-lane/query top-9 extraction.
// Row r <-> point m = n0-90+r. Query q (n = n0+q) = row q+90.
// Window candidate m = n-89+wofs = row q+1+wofs, wofs in [0,89]; rel = r-q-1.
// Garbage-safety: rows with m<0 or m>=NPTS are staged unmasked (clamped addr);
// their keys are either never packed (rel out of [0,89]) or masked to MAX in
// selection (m<0 check) - so no load masking is needed anywhere.
__global__ __launch_bounds__(512, 4) void knn_fused(const float* __restrict__ x,
                                                    int* __restrict__ out) {
    __shared__ uint32_t ud[BQ * UD2];      // 23296 B keys [q][wofs]; head doubles as psum
    __shared__ ushort   sb[RROWS * SD2];   // 23040 B staged bf16 rows
    __shared__ float    rnArr[RROWS];      // 640 B inverse norms

    float2* psumA = (float2*)ud;           // [512] row-pair partials (region 1)
    float2* psumB = (float2*)ud + 512;     // [128] = 8 waves x 16 row-pair partials (reg 2)

    const int tid = threadIdx.x;
    // XCD-chunked swizzle: same-XCD blocks take consecutive tiles -> window L2 hits
    const int blk = blockIdx.x;
    const int L   = (blk & 7) * 64 + (blk >> 3);   // bijective on 512 blocks
    const int b   = L >> 7;                        // 128 tiles per batch
    const int n0  = (L & 127) << 6;
    const int gbase = n0 - 90;                     // EVEN

    const float* xb = x + (size_t)b * DIM * NPTS;

    const int w = tid >> 6;
    const int l = tid & 63;

    // ---- stage region 1: rows 0..127 as 64 lane-pairs; wave w covers d in [8w,8w+7] ----
    // Each float2 load: 64 lanes x 8 B consecutive n -> 512 B contiguous segment.
    {
        const int g2 = l * 2;                      // row pair (g2, g2+1)
        const int gg = gbase + g2;
        const int gs = (gg < 0) ? 0 : gg;          // clamp only; no value masking
        const float* src = xb + gs;
        float s0 = 0.f, s1 = 0.f;
        uint32_t pkA[4], pkB[4];
#pragma unroll
        for (int e = 0; e < 4; ++e) {
            const int d = 8 * w + 2 * e;
            float2 v = *reinterpret_cast<const float2*>(&src[(size_t)d * NPTS]);
            float2 u = *reinterpret_cast<const float2*>(&src[(size_t)(d + 1) * NPTS]);
            s0 += v.x * v.x + u.x * u.x;
            s1 += v.y * v.y + u.y * u.y;
            __hip_bfloat162 hA = __float22bfloat162_rn(make_float2(v.x, u.x));
            __hip_bfloat162 hB = __float22bfloat162_rn(make_float2(v.y, u.y));
            pkA[e] = *reinterpret_cast<uint32_t*>(&hA);
            pkB[e] = *reinterpret_cast<uint32_t*>(&hB);
        }
        *reinterpret_cast<uint4*>(&sb[(size_t)g2 * SD2 + 8 * w]) =
            make_uint4(pkA[0], pkA[1], pkA[2], pkA[3]);
        *reinterpret_cast<uint4*>(&sb[(size_t)(g2 + 1) * SD2 + 8 * w]) =
            make_uint4(pkB[0], pkB[1], pkB[2], pkB[3]);
        psumA[tid] = make_float2(s0, s1);
    }
    // ---- stage region 2: rows 128..159 as 16 lane-pairs x 32 d-pairs ----
    {
        const int g2 = 128 + (l & 15) * 2;
        const int c  = (w << 2) | (l >> 4);        // 0..31: d pair (2c, 2c+1)
        const int gg = gbase + g2;                 // >= 38 always
        const int gs = (gg > NPTS - 2) ? (NPTS - 2) : gg;
        const float* src = xb + gs;
        float2 v = *reinterpret_cast<const float2*>(&src[(size_t)(2 * c) * NPTS]);
        float2 u = *reinterpret_cast<const float2*>(&src[(size_t)(2 * c + 1) * NPTS]);
        float s0 = v.x * v.x + u.x * u.x;
        float s1 = v.y * v.y + u.y * u.y;
        __hip_bfloat162 hA = __float22bfloat162_rn(make_float2(v.x, u.x));
        __hip_bfloat162 hB = __float22bfloat162_rn(make_float2(v.y, u.y));
        *reinterpret_cast<uint32_t*>(&sb[(size_t)g2 * SD2 + 2 * c]) =
            *reinterpret_cast<uint32_t*>(&hA);
        *reinterpret_cast<uint32_t*>(&sb[(size_t)(g2 + 1) * SD2 + 2 * c]) =
            *reinterpret_cast<uint32_t*>(&hB);
        // in-wave pre-reduce over the 4 c-values sharing this row pair (lanes l, l^16, l^32)
        s0 += __shfl_xor(s0, 16); s0 += __shfl_xor(s0, 32);
        s1 += __shfl_xor(s1, 16); s1 += __shfl_xor(s1, 32);
        if (l < 16) psumB[w * 16 + l] = make_float2(s0, s1);
    }
    __syncthreads();   // bar1: sb + psum visible

    // ---- A-frag prefetch (sb valid) overlapped with inverse-norm reduce ----
    const int qt = w >> 1;            // query tile 0..3
    const int h  = w & 1;             // row-tile half
    const int lr = l & 15;
    const int lk = l >> 4;
    const int nrt = 4 - h;            // 4 or 3 row tiles (band rows 16qt .. 16qt+111)

    const ushort* ap = &sb[(size_t)(90 + qt * 16 + lr) * SD2 + lk * 8];
    bf16x8 a0 = *reinterpret_cast<const bf16x8*>(ap);
    bf16x8 a1 = *reinterpret_cast<const bf16x8*>(ap + 32);

    if (tid < 128) {
        const int gp = tid >> 1, comp = tid & 1;
        float s = 0.f;
#pragma unroll
        for (int k = 0; k < 8; ++k)
            s += reinterpret_cast<const float*>(&psumA[k * 64 + gp])[comp];
        rnArr[tid] = 1.0f / fmaxf(sqrtf(s), 1e-12f);
    } else if (tid < 160) {
        const int rr = tid - 128;
        const int gp = rr >> 1, comp = rr & 1;
        float s = 0.f;
#pragma unroll
        for (int k = 0; k < 8; ++k)
            s += reinterpret_cast<const float*>(&psumB[k * 16 + gp])[comp];
        rnArr[tid] = 1.0f / fmaxf(sqrtf(s), 1e-12f);
    }
    __syncthreads();   // bar2: rnArr visible; psum dead (ud writes now safe)

    // ---- banded MFMA (nrt split) + compact key pack ----
    {
        float rq[4];
#pragma unroll
        for (int j = 0; j < 4; ++j) rq[j] = rnArr[90 + qt * 16 + lk * 4 + j];
        const int q0 = qt * 16 + lk * 4;
        __builtin_amdgcn_s_setprio(1);     // favor MFMA-issuing wave vs other block's phases
#pragma unroll
        for (int i = 0; i < 4; ++i) {
            if (i < nrt) {
                const int rto = h * 4 + i;
                const int rbase = qt * 16 + rto * 16;
                const ushort* bp = &sb[(size_t)(rbase + lr) * SD2 + lk * 8];
                bf16x8 b0 = *reinterpret_cast<const bf16x8*>(bp);
                bf16x8 b1 = *reinterpret_cast<const bf16x8*>(bp + 32);
                f32x4 acc = {0.f, 0.f, 0.f, 0.f};
                acc = __builtin_amdgcn_mfma_f32_16x16x32_bf16(a0, b0, acc, 0, 0, 0);
                acc = __builtin_amdgcn_mfma_f32_16x16x32_bf16(a1, b1, acc, 0, 0, 0);
                const int r = rbase + lr;
                const float rnr = rnArr[r];
#pragma unroll
                for (int j = 0; j < 4; ++j) {
                    int rel = r - (q0 + j) - 1;      // window offset wofs
                    if (rel >= 0 && rel <= 89) {
                        float p = acc[j] * rq[j] * rnr;
                        float dist = 2.0f - 2.0f * p;
                        uint32_t uu = __float_as_uint(dist);
                        uu = (uu & 0x80000000u) ? ~uu : (uu | 0x80000000u);
                        ud[(q0 + j) * UD2 + rel] = (uu & 0xFFFFFF80u) | (uint32_t)rel;
                    }
                }
            }
        }
        __builtin_amdgcn_s_setprio(0);
    }
    __syncthreads();   // bar3: keys visible

    // ---- selection: 8 lanes per query, 9 rounds of masked-min extraction ----
    {
        const int ql = l >> 3;             // 0..7
        const int s  = l & 7;              // 0..7
        const int q  = (w << 3) | ql;      // 0..63
        const int n  = n0 + q;

        uint32_t key[12];
#pragma unroll
        for (int t = 0; t < 12; ++t) {
            int wofs = s + 8 * t;          // window offset 0..95
            int m = n - 89 + wofs;
            bool ok = (wofs <= 89) && (m >= 0);
            uint32_t raw = ud[q * UD2 + (ok ? wofs : 0)];
            key[t] = ok ? raw : 0xFFFFFFFFu;
        }

        uint32_t prev = 0;
        int omKeep = n;
        int om8 = n;
#pragma unroll
        for (int j = 0; j < KK; ++j) {
            uint32_t cc[12];
#pragma unroll
            for (int t = 0; t < 12; ++t)
                cc[t] = (key[t] > prev) ? key[t] : 0xFFFFFFFFu;
            // depth-4 tree (v_min3-friendly): bit-identical to sequential min
            uint32_t g0 = umin32(umin32(cc[0], cc[1]), cc[2]);
            uint32_t g1 = umin32(umin32(cc[3], cc[4]), cc[5]);
            uint32_t g2 = umin32(umin32(cc[6], cc[7]), cc[8]);
            uint32_t g3 = umin32(umin32(cc[9], cc[10]), cc[11]);
            uint32_t mn = umin32(umin32(g0, g1), umin32(g2, g3));
            uint32_t o;
            o = (uint32_t)__shfl_xor((int)mn, 1); mn = umin32(o, mn);
            o = (uint32_t)__shfl_xor((int)mn, 2); mn = umin32(o, mn);
            o = (uint32_t)__shfl_xor((int)mn, 4); mn = umin32(o, mn);
            int om = (mn == 0xFFFFFFFFu) ? n : (n - 89 + (int)(mn & 127u));
            if (j < 8) {
                if (s == j) omKeep = om;
            } else {
                om8 = om;
            }
            prev = mn;
        }

        const int base0 = (b * NPTS + n) * KK;
        const int base1 = NB * NPTS * KK + base0;
        out[base0 + s] = omKeep;           // 8 coalesced lanes per query
        out[base1 + s] = n;
        if (s == 0) {
            out[base0 + 8] = om8;
            out[base1 + 8] = n;
        }
    }
}

extern "C" void kernel_launch(void* const* d_in, const int* in_sizes, int n_in,
                              void* d_out, int out_size, void* d_ws, size_t ws_size,
                              hipStream_t stream) {
    const float* x = (const float*)d_in[0];
    int* out = (int*)d_out;
    knn_fused<<<NB * (NPTS / BQ), 512, 0, stream>>>(x, out);
}

// Round 9
// 12.533 us; speedup vs baseline: 1.2451x; 1.0368x over previous
//
#include <hip/hip_runtime.h>
#include <hip/hip_bf16.h>
#include <stdint.h>

#define NPTS 8192
#define DIM  64
#define NB   4
#define KK   9
#define BQ   64       // queries per block
#define RROWS 160     // staged rows: m = n0-90+r (row 0 = pad so gbase is EVEN)
#define SD2  72       // stage row stride in bf16 elems (144 B, 16B-aligned)
#define UD2  91       // key stride per query (uints): wofs 0..89 + pad

typedef short bf16x8 __attribute__((ext_vector_type(8)));
typedef float f32x4  __attribute__((ext_vector_type(4)));

static __device__ __forceinline__ uint32_t umin32(uint32_t a, uint32_t b) {
    return a < b ? a : b;
}

// DPP lane-xor within 8-lane groups (pure VALU, no LDS pipe):
// xor1 = quad_perm[1,0,3,2] (0xB1), xor2 = quad_perm[2,3,0,1] (0x4E),
// xor7 = row_half_mirror (0x141). After xor1+xor2 each quad holds its quad-min;
// partner s^7 is in the other quad, so min(self, s^7) = min of all 8 lanes
// (bit-identical to the shfl_xor 1/2/4 reduction: same 8 distinct values).
#define DPP_MIN(mn, ctrl)                                                         \
    mn = umin32((uint32_t)__builtin_amdgcn_update_dpp((int)(mn), (int)(mn),       \
                                                      (ctrl), 0xF, 0xF, false),  \
                (mn))

// 3-barrier fused KNN (R8 = 12.99us), selection shuffles moved to DPP:
//   stage bf16 (float2 pair loads, clamped unmasked) + psum -> bar1 ->
//   A-frag prefetch || psum reduce -> bar2 ->
//   banded MFMA (nrt split, setprio 1) + key pack -> bar3 ->
//   8-lane/query top-9 extraction (tree-min + DPP reduce).
// Row r <-> point m = n0-90+r. Query q (n = n0+q) = row q+90.
// Window candidate m = n-89+wofs = row q+1+wofs, wofs in [0,89]; rel = r-q-1.
// Garbage-safety: rows with m<0 or m>=NPTS are staged unmasked (clamped addr);
// their keys are either never packed (rel out of [0,89]) or masked to MAX in
// selection (m<0 check) - so no load masking is needed anywhere.
__global__ __launch_bounds__(512, 4) void knn_fused(const float* __restrict__ x,
                                                    int* __restrict__ out) {
    __shared__ uint32_t ud[BQ * UD2];      // 23296 B keys [q][wofs]; head doubles as psum
    __shared__ ushort   sb[RROWS * SD2];   // 23040 B staged bf16 rows
    __shared__ float    rnArr[RROWS];      // 640 B inverse norms

    float2* psumA = (float2*)ud;           // [512] row-pair partials (region 1)
    float2* psumB = (float2*)ud + 512;     // [128] = 8 waves x 16 row-pair partials (reg 2)

    const int tid = threadIdx.x;
    // XCD-chunked swizzle: same-XCD blocks take consecutive tiles -> window L2 hits
    const int blk = blockIdx.x;
    const int L   = (blk & 7) * 64 + (blk >> 3);   // bijective on 512 blocks
    const int b   = L >> 7;                        // 128 tiles per batch
    const int n0  = (L & 127) << 6;
    const int gbase = n0 - 90;                     // EVEN

    const float* xb = x + (size_t)b * DIM * NPTS;

    const int w = tid >> 6;
    const int l = tid & 63;

    // ---- stage region 1: rows 0..127 as 64 lane-pairs; wave w covers d in [8w,8w+7] ----
    // Each float2 load: 64 lanes x 8 B consecutive n -> 512 B contiguous segment.
    {
        const int g2 = l * 2;                      // row pair (g2, g2+1)
        const int gg = gbase + g2;
        const int gs = (gg < 0) ? 0 : gg;          // clamp only; no value masking
        const float* src = xb + gs;
        float s0 = 0.f, s1 = 0.f;
        uint32_t pkA[4], pkB[4];
#pragma unroll
        for (int e = 0; e < 4; ++e) {
            const int d = 8 * w + 2 * e;
            float2 v = *reinterpret_cast<const float2*>(&src[(size_t)d * NPTS]);
            float2 u = *reinterpret_cast<const float2*>(&src[(size_t)(d + 1) * NPTS]);
            s0 += v.x * v.x + u.x * u.x;
            s1 += v.y * v.y + u.y * u.y;
            __hip_bfloat162 hA = __float22bfloat162_rn(make_float2(v.x, u.x));
            __hip_bfloat162 hB = __float22bfloat162_rn(make_float2(v.y, u.y));
            pkA[e] = *reinterpret_cast<uint32_t*>(&hA);
            pkB[e] = *reinterpret_cast<uint32_t*>(&hB);
        }
        *reinterpret_cast<uint4*>(&sb[(size_t)g2 * SD2 + 8 * w]) =
            make_uint4(pkA[0], pkA[1], pkA[2], pkA[3]);
        *reinterpret_cast<uint4*>(&sb[(size_t)(g2 + 1) * SD2 + 8 * w]) =
            make_uint4(pkB[0], pkB[1], pkB[2], pkB[3]);
        psumA[tid] = make_float2(s0, s1);
    }
    // ---- stage region 2: rows 128..159 as 16 lane-pairs x 32 d-pairs ----
    {
        const int g2 = 128 + (l & 15) * 2;
        const int c  = (w << 2) | (l >> 4);        // 0..31: d pair (2c, 2c+1)
        const int gg = gbase + g2;                 // >= 38 always
        const int gs = (gg > NPTS - 2) ? (NPTS - 2) : gg;
        const float* src = xb + gs;
        float2 v = *reinterpret_cast<const float2*>(&src[(size_t)(2 * c) * NPTS]);
        float2 u = *reinterpret_cast<const float2*>(&src[(size_t)(2 * c + 1) * NPTS]);
        float s0 = v.x * v.x + u.x * u.x;
        float s1 = v.y * v.y + u.y * u.y;
        __hip_bfloat162 hA = __float22bfloat162_rn(make_float2(v.x, u.x));
        __hip_bfloat162 hB = __float22bfloat162_rn(make_float2(v.y, u.y));
        *reinterpret_cast<uint32_t*>(&sb[(size_t)g2 * SD2 + 2 * c]) =
            *reinterpret_cast<uint32_t*>(&hA);
        *reinterpret_cast<uint32_t*>(&sb[(size_t)(g2 + 1) * SD2 + 2 * c]) =
            *reinterpret_cast<uint32_t*>(&hB);
        // in-wave pre-reduce over the 4 c-values sharing this row pair (lanes l, l^16, l^32)
        s0 += __shfl_xor(s0, 16); s0 += __shfl_xor(s0, 32);
        s1 += __shfl_xor(s1, 16); s1 += __shfl_xor(s1, 32);
        if (l < 16) psumB[w * 16 + l] = make_float2(s0, s1);
    }
    __syncthreads();   // bar1: sb + psum visible

    // ---- A-frag prefetch (sb valid) overlapped with inverse-norm reduce ----
    const int qt = w >> 1;            // query tile 0..3
    const int h  = w & 1;             // row-tile half
    const int lr = l & 15;
    const int lk = l >> 4;
    const int nrt = 4 - h;            // 4 or 3 row tiles (band rows 16qt .. 16qt+111)

    const ushort* ap = &sb[(size_t)(90 + qt * 16 + lr) * SD2 + lk * 8];
    bf16x8 a0 = *reinterpret_cast<const bf16x8*>(ap);
    bf16x8 a1 = *reinterpret_cast<const bf16x8*>(ap + 32);

    if (tid < 128) {
        const int gp = tid >> 1, comp = tid & 1;
        float s = 0.f;
#pragma unroll
        for (int k = 0; k < 8; ++k)
            s += reinterpret_cast<const float*>(&psumA[k * 64 + gp])[comp];
        rnArr[tid] = 1.0f / fmaxf(sqrtf(s), 1e-12f);
    } else if (tid < 160) {
        const int rr = tid - 128;
        const int gp = rr >> 1, comp = rr & 1;
        float s = 0.f;
#pragma unroll
        for (int k = 0; k < 8; ++k)
            s += reinterpret_cast<const float*>(&psumB[k * 16 + gp])[comp];
        rnArr[tid] = 1.0f / fmaxf(sqrtf(s), 1e-12f);
    }
    __syncthreads();   // bar2: rnArr visible; psum dead (ud writes now safe)

    // ---- banded MFMA (nrt split) + compact key pack ----
    {
        float rq[4];
#pragma unroll
        for (int j = 0; j < 4; ++j) rq[j] = rnArr[90 + qt * 16 + lk * 4 + j];
        const int q0 = qt * 16 + lk * 4;
        __builtin_amdgcn_s_setprio(1);     // favor MFMA-issuing wave vs other block's phases
#pragma unroll
        for (int i = 0; i < 4; ++i) {
            if (i < nrt) {
                const int rto = h * 4 + i;
                const int rbase = qt * 16 + rto * 16;
                const ushort* bp = &sb[(size_t)(rbase + lr) * SD2 + lk * 8];
                bf16x8 b0 = *reinterpret_cast<const bf16x8*>(bp);
                bf16x8 b1 = *reinterpret_cast<const bf16x8*>(bp + 32);
                f32x4 acc = {0.f, 0.f, 0.f, 0.f};
                acc = __builtin_amdgcn_mfma_f32_16x16x32_bf16(a0, b0, acc, 0, 0, 0);
                acc = __builtin_amdgcn_mfma_f32_16x16x32_bf16(a1, b1, acc, 0, 0, 0);
                const int r = rbase + lr;
                const float rnr = rnArr[r];
#pragma unroll
                for (int j = 0; j < 4; ++j) {
                    int rel = r - (q0 + j) - 1;      // window offset wofs
                    if (rel >= 0 && rel <= 89) {
                        float p = acc[j] * rq[j] * rnr;
                        float dist = 2.0f - 2.0f * p;
                        uint32_t uu = __float_as_uint(dist);
                        uu = (uu & 0x80000000u) ? ~uu : (uu | 0x80000000u);
                        ud[(q0 + j) * UD2 + rel] = (uu & 0xFFFFFF80u) | (uint32_t)rel;
                    }
                }
            }
        }
        __builtin_amdgcn_s_setprio(0);
    }
    __syncthreads();   // bar3: keys visible

    // ---- selection: 8 lanes per query, 9 rounds of masked-min extraction ----
    {
        const int ql = l >> 3;             // 0..7
        const int s  = l & 7;              // 0..7
        const int q  = (w << 3) | ql;      // 0..63
        const int n  = n0 + q;

        uint32_t key[12];
#pragma unroll
        for (int t = 0; t < 12; ++t) {
            int wofs = s + 8 * t;          // window offset 0..95
            int m = n - 89 + wofs;
            bool ok = (wofs <= 89) && (m >= 0);
            uint32_t raw = ud[q * UD2 + (ok ? wofs : 0)];
            key[t] = ok ? raw : 0xFFFFFFFFu;
        }

        uint32_t prev = 0;
        int omKeep = n;
        int om8 = n;
#pragma unroll
        for (int j = 0; j < KK; ++j) {
            uint32_t cc[12];
#pragma unroll
            for (int t = 0; t < 12; ++t)
                cc[t] = (key[t] > prev) ? key[t] : 0xFFFFFFFFu;
            // depth-4 tree (v_min3-friendly): bit-identical to sequential min
            uint32_t g0 = umin32(umin32(cc[0], cc[1]), cc[2]);
            uint32_t g1 = umin32(umin32(cc[3], cc[4]), cc[5]);
            uint32_t g2 = umin32(umin32(cc[6], cc[7]), cc[8]);
            uint32_t g3 = umin32(umin32(cc[9], cc[10]), cc[11]);
            uint32_t mn = umin32(umin32(g0, g1), umin32(g2, g3));
            // 8-lane min reduce on the VALU pipe (DPP), no LDS traffic
            DPP_MIN(mn, 0xB1);             // quad_perm [1,0,3,2]  (xor 1)
            DPP_MIN(mn, 0x4E);             // quad_perm [2,3,0,1]  (xor 2)
            DPP_MIN(mn, 0x141);            // row_half_mirror      (xor 7)
            int om = (mn == 0xFFFFFFFFu) ? n : (n - 89 + (int)(mn & 127u));
            if (j < 8) {
                if (s == j) omKeep = om;
            } else {
                om8 = om;
            }
            prev = mn;
        }

        const int base0 = (b * NPTS + n) * KK;
        const int base1 = NB * NPTS * KK + base0;
        out[base0 + s] = omKeep;           // 8 coalesced lanes per query
        out[base1 + s] = n;
        if (s == 0) {
            out[base0 + 8] = om8;
            out[base1 + 8] = n;
        }
    }
}

extern "C" void kernel_launch(void* const* d_in, const int* in_sizes, int n_in,
                              void* d_out, int out_size, void* d_ws, size_t ws_size,
                              hipStream_t stream) {
    const float* x = (const float*)d_in[0];
    int* out = (int*)d_out;
    knn_fused<<<NB * (NPTS / BQ), 512, 0, stream>>>(x, out);
}